// Round 1
// baseline (99.570 us; speedup 1.0000x reference)
//
#include <hip/hip_runtime.h>

// Problem constants (from reference): onsets (B, T, N, C) float32
#define B_ 64
#define T_ 8192
#define N_ 16
#define C_ 2
#define TILE 256              // t-values per block (1 per thread)
#define NT (T_ / TILE)        // 32 tiles per batch row

// K1: per-tile onset detection + block-local inclusive prefix-max scan.
// Writes provisional out (correct for all t at/after the tile's first onset),
// plus tileMax (max onset index in tile, or -1) and firstOnset (global t of
// first onset in tile, or INT_MAX).
__global__ __launch_bounds__(TILE) void k1_scan(const float* __restrict__ onsets,
                                                float* __restrict__ out,
                                                int* __restrict__ tileMax,
                                                int* __restrict__ firstOnset) {
    __shared__ int s[TILE];
    const int blk  = blockIdx.x;
    const int b    = blk / NT;
    const int tile = blk % NT;
    const int tid  = threadIdx.x;
    const int t    = tile * TILE + tid;

    // 128 contiguous bytes per t: 16 notes x 2 channels. Channel 0 is .x/.z.
    const float4* p = (const float4*)onsets + (size_t)(b * T_ + t) * (N_ * C_ / 4);
    float m = 0.0f;
#pragma unroll
    for (int i = 0; i < 8; ++i) {
        float4 v = p[i];
        m = fmaxf(m, fmaxf(v.x, v.z));
    }
    const bool onset = (m > 0.0f);
    int idx = onset ? t : -1;

    // Block-wide inclusive prefix-max (Hillis-Steele in LDS, 8 steps).
    s[tid] = idx;
    __syncthreads();
#pragma unroll
    for (int off = 1; off < TILE; off <<= 1) {
        int u = (tid >= off) ? s[tid - off] : -1;
        int v = s[tid];
        __syncthreads();
        s[tid] = (u > v) ? u : v;
        __syncthreads();
    }
    const int last = s[tid];             // tile-local last onset (global index), -1 if none yet
    out[b * T_ + t] = (float)(t - last); // provisional: wrong only for t < firstOnset (fixed by K2)

    if (tid == TILE - 1) tileMax[blk] = last;  // inclusive scan at last thread == tile max

    // firstOnset via block min-reduce over (onset ? t : INT_MAX)
    s[tid] = onset ? t : 0x7fffffff;
    __syncthreads();
#pragma unroll
    for (int off = TILE / 2; off > 0; off >>= 1) {
        if (tid < off) {
            int a = s[tid], c = s[tid + off];
            s[tid] = (c < a) ? c : a;
        }
        __syncthreads();
    }
    if (tid == 0) firstOnset[blk] = s[0];
}

// K2: compute cross-tile carry (exclusive prefix-max of tileMax along the row,
// seeded with the virtual onset at -1) and rewrite only the head of each tile
// (t < firstOnset), where K1's local scan had no onset to anchor on.
__global__ __launch_bounds__(TILE) void k2_fixup(const int* __restrict__ tileMax,
                                                 const int* __restrict__ firstOnset,
                                                 float* __restrict__ out) {
    const int blk  = blockIdx.x;
    const int b    = blk / NT;
    const int tile = blk % NT;
    const int tid  = threadIdx.x;

    __shared__ int red[NT];
    __shared__ int carry_s;
    if (tid < NT) red[tid] = -1;
    __syncthreads();
    if (tid < tile) red[tid] = tileMax[b * NT + tid];   // preceding tiles only
    __syncthreads();
    if (tid == 0) {
        int c = -1;
#pragma unroll
        for (int i = 0; i < NT; ++i) c = (red[i] > c) ? red[i] : c;
        carry_s = c;
    }
    __syncthreads();

    const int f = firstOnset[blk];      // global t of first onset in this tile (INT_MAX if none)
    const int t = tile * TILE + tid;
    if (t < f) out[b * T_ + t] = (float)(t - carry_s);
}

extern "C" void kernel_launch(void* const* d_in, const int* in_sizes, int n_in,
                              void* d_out, int out_size, void* d_ws, size_t ws_size,
                              hipStream_t stream) {
    const float* onsets = (const float*)d_in[0];
    float* out = (float*)d_out;

    int* tileMax    = (int*)d_ws;           // B_*NT ints = 8 KB
    int* firstOnset = tileMax + B_ * NT;    // B_*NT ints = 8 KB

    dim3 grid(B_ * NT);
    k1_scan<<<grid, TILE, 0, stream>>>(onsets, out, tileMax, firstOnset);
    k2_fixup<<<grid, TILE, 0, stream>>>(tileMax, firstOnset, out);
}

// Round 3
// 93.627 us; speedup vs baseline: 1.0635x; 1.0635x over previous
//
#include <hip/hip_runtime.h>

// onsets (B, T, N, C) float32; out[b,t] = t - (last onset index <= t, else -1)
#define B_ 64
#define T_ 8192
#define N_ 16
#define C_ 2
#define TILE 256              // t-values per block (1 per thread)
#define NT (T_ / TILE)        // 32 tiles per batch row

// K1: coalesced onset detection + 2-barrier block scan.
// Wave w handles t_local in [w*64, w*64+64). Data per block = 32 KB contiguous.
// Load pattern: float4 index = w*512 + j*64 + lane -> 1024B/instr coalesced.
// For fixed j, lanes 8k..8k+7 hold the 8 float4 of t_local = w*64 + j*8 + k.
__global__ __launch_bounds__(TILE) void k1_scan(const float* __restrict__ onsets,
                                                float* __restrict__ out,
                                                int* __restrict__ tileMax,
                                                int* __restrict__ firstOnset) {
    const int blk  = blockIdx.x;
    const int b    = blk >> 5;         // / NT
    const int tile = blk & (NT - 1);
    const int tid  = threadIdx.x;
    const int wave = tid >> 6;
    const int lane = tid & 63;

    __shared__ unsigned char flags[TILE];
    __shared__ int wmax[4];
    __shared__ int wfirst[4];

    const float4* base4 = (const float4*)onsets + ((size_t)(b * T_ + tile * TILE) << 3);

#pragma unroll
    for (int j = 0; j < 8; ++j) {
        float4 v = base4[(wave << 9) + (j << 6) + lane];
        float mm = fmaxf(v.x, v.z);                 // channel 0 lives in .x/.z
        mm = fmaxf(mm, __shfl_xor(mm, 1));          // 8-lane group max
        mm = fmaxf(mm, __shfl_xor(mm, 2));
        mm = fmaxf(mm, __shfl_xor(mm, 4));
        if ((lane & 7) == 0)
            flags[(wave << 6) + (j << 3) + (lane >> 3)] = (mm > 0.0f) ? 1 : 0;
    }
    __syncthreads();

    // Scan phase: thread tid owns t_local = tid (= wave*64 + lane, t-ordered).
    const int t  = tile * TILE + tid;
    const bool on = flags[tid] != 0;
    int idx = on ? t : -1;
#pragma unroll
    for (int off = 1; off < 64; off <<= 1) {        // wave inclusive max-scan
        int u = __shfl_up(idx, off);
        if (lane >= off) idx = (u > idx) ? u : idx;
    }
    if (lane == 63) wmax[wave] = idx;               // wave total
    unsigned long long bal = __ballot(on);
    if (lane == 0)
        wfirst[wave] = bal ? (tile * TILE + (wave << 6) + __ffsll(bal) - 1) : 0x7fffffff;
    __syncthreads();

    int carry = -1;                                  // max over preceding waves
#pragma unroll
    for (int w = 0; w < 4; ++w) {
        int v = wmax[w];
        if (w < wave && v > carry) carry = v;
    }
    const int last = (carry > idx) ? carry : idx;
    out[b * T_ + t] = (float)(t - last);             // wrong only for t < firstOnset of tile

    if (tid == 0) {
        int bm = wmax[0], f = wfirst[0];
#pragma unroll
        for (int w = 1; w < 4; ++w) {
            bm = (wmax[w] > bm) ? wmax[w] : bm;
            f  = (wfirst[w] < f) ? wfirst[w] : f;
        }
        tileMax[blk]    = bm;
        firstOnset[blk] = f;
    }
}

// K2: carry = max(tileMax of preceding tiles in row); rewrite only t < firstOnset.
__global__ __launch_bounds__(TILE) void k2_fixup(const int* __restrict__ tileMax,
                                                 const int* __restrict__ firstOnset,
                                                 float* __restrict__ out) {
    const int blk  = blockIdx.x;
    const int b    = blk >> 5;
    const int tile = blk & (NT - 1);
    const int tid  = threadIdx.x;

    __shared__ int carry_s;
    if (tid < 64) {
        int v = (tid < tile) ? tileMax[(b << 5) + tid] : -1;   // preceding tiles only
#pragma unroll
        for (int off = 32; off; off >>= 1) {
            int u = __shfl_xor(v, off);
            v = (u > v) ? u : v;
        }
        if (tid == 0) carry_s = v;
    }
    __syncthreads();

    const int f = firstOnset[blk];     // INT_MAX if tile has no onset
    const int t = tile * TILE + tid;
    if (t < f) out[b * T_ + t] = (float)(t - carry_s);
}

extern "C" void kernel_launch(void* const* d_in, const int* in_sizes, int n_in,
                              void* d_out, int out_size, void* d_ws, size_t ws_size,
                              hipStream_t stream) {
    const float* onsets = (const float*)d_in[0];
    float* out = (float*)d_out;

    int* tileMax    = (int*)d_ws;           // B_*NT ints = 8 KB
    int* firstOnset = tileMax + B_ * NT;    // B_*NT ints = 8 KB

    dim3 grid(B_ * NT);
    k1_scan<<<grid, TILE, 0, stream>>>(onsets, out, tileMax, firstOnset);
    k2_fixup<<<grid, TILE, 0, stream>>>(tileMax, firstOnset, out);
}

// Round 4
// 91.662 us; speedup vs baseline: 1.0863x; 1.0214x over previous
//
#include <hip/hip_runtime.h>

// onsets (B, T, N, C=2) float32; out[b,t] = t - (last onset index <= t, else -1)
// onset at frame t  <=>  max_n onsets[b,t,n,0] > 0. Channel 0 = .x/.z of each float4.
#define B_ 64
#define T_ 8192
#define N_ 16
#define TILE 256              // frames per block (1 per thread)
#define NT (T_ / TILE)        // 32 tiles per batch row

// Single fused kernel:
//  1. coalesced tile load (8 x 1KB/wave-instr), per-frame onset flag via 8-lane shfl max
//  2. wave shfl_up inclusive max-scan + cross-wave carry (2 barriers)
//  3. cross-TILE carry: backward scan of the raw input (L3-resident, 64MiB < 256MiB L3)
//     in coalesced 32-frame / 4KB chunks. P(chunk empty) ~= 0.077, so ~1.1 iters typ.
//     No workspace, no second kernel, no inter-block communication.
__global__ __launch_bounds__(TILE) void k_fused(const float* __restrict__ onsets,
                                                float* __restrict__ out) {
    const int blk  = blockIdx.x;
    const int b    = blk >> 5;          // / NT
    const int tile = blk & (NT - 1);
    const int tid  = threadIdx.x;
    const int wave = tid >> 6;
    const int lane = tid & 63;

    __shared__ unsigned char flags[TILE];
    __shared__ int wmax[4];
    __shared__ int wtmp[4];

    const float4* row4  = (const float4*)onsets + (size_t)b * (T_ * 8);  // 8 float4 per frame
    const float4* base4 = row4 + (size_t)(tile * TILE) * 8;

    // --- 1. tile load + onset flags (fully coalesced) ---
#pragma unroll
    for (int j = 0; j < 8; ++j) {
        float4 v = base4[(wave << 9) + (j << 6) + lane];
        float mm = fmaxf(v.x, v.z);
        mm = fmaxf(mm, __shfl_xor(mm, 1));      // 8-lane group max -> frame max
        mm = fmaxf(mm, __shfl_xor(mm, 2));
        mm = fmaxf(mm, __shfl_xor(mm, 4));
        if ((lane & 7) == 0)
            flags[(wave << 6) + (j << 3) + (lane >> 3)] = (mm > 0.0f) ? 1 : 0;
    }
    __syncthreads();

    // --- 2. block inclusive max-scan over onset indices ---
    const int t  = tile * TILE + tid;
    const bool on = flags[tid] != 0;
    int idx = on ? t : -1;
#pragma unroll
    for (int off = 1; off < 64; off <<= 1) {
        int u = __shfl_up(idx, off);
        if (lane >= off) idx = (u > idx) ? u : idx;
    }
    if (lane == 63) wmax[wave] = idx;
    const bool needCarry = (tile > 0) && (flags[0] == 0);   // block-uniform
    __syncthreads();

    int carry = -1;                              // max onset over preceding waves in tile
#pragma unroll
    for (int w = 0; w < 4; ++w) {
        int v = wmax[w];
        if (w < wave && v > carry) carry = v;
    }

    // --- 3. cross-tile carry via backward input scan (block-uniform branch) ---
    if (needCarry) {
        int cs = tile * TILE - 32;               // chunk start frame
        for (;;) {
            // block reads frames [cs, cs+32): thread tid -> float4 cs*8 + tid (4KB coalesced)
            float4 v = row4[(size_t)cs * 8 + tid];
            float mm = fmaxf(v.x, v.z);
            mm = fmaxf(mm, __shfl_xor(mm, 1));
            mm = fmaxf(mm, __shfl_xor(mm, 2));
            mm = fmaxf(mm, __shfl_xor(mm, 4));
            // leader lane of each 8-lane group owns frame cs + wave*8 + lane/8
            unsigned long long bal = __ballot(((lane & 7) == 0) && (mm > 0.0f));
            if (lane == 0) {
                int wbest = -1;
                if (bal) {
                    int hb = 63 - __clzll(bal);              // highest onset lane in wave
                    wbest = cs + (wave << 3) + (hb >> 3);
                }
                wtmp[wave] = wbest;
            }
            __syncthreads();
            int bbest = wtmp[0];
            bbest = (wtmp[1] > bbest) ? wtmp[1] : bbest;
            bbest = (wtmp[2] > bbest) ? wtmp[2] : bbest;
            bbest = (wtmp[3] > bbest) ? wtmp[3] : bbest;
            if (bbest >= 0 || cs == 0) {
                if (bbest > carry) carry = bbest;
                break;
            }
            cs -= 32;
            __syncthreads();                      // protect wtmp reuse next iter
        }
    }

    // --- final: one write per frame ---
    const int last = (carry > idx) ? carry : idx;
    out[b * T_ + t] = (float)(t - last);
}

extern "C" void kernel_launch(void* const* d_in, const int* in_sizes, int n_in,
                              void* d_out, int out_size, void* d_ws, size_t ws_size,
                              hipStream_t stream) {
    const float* onsets = (const float*)d_in[0];
    float* out = (float*)d_out;
    k_fused<<<dim3(B_ * NT), TILE, 0, stream>>>(onsets, out);
}